// Round 8
// baseline (139.472 us; speedup 1.0000x reference)
//
#include <hip/hip_runtime.h>

#define BATCH 512
#define DIM   256
#define UNITS 256

typedef __bf16 bf16x8 __attribute__((ext_vector_type(8)));
typedef float  f32x4  __attribute__((ext_vector_type(4)));

__device__ __forceinline__ bf16x8 ld_bf8(const unsigned short* p) {
    uint4 u = *reinterpret_cast<const uint4*>(p);
    return __builtin_bit_cast(bf16x8, u);
}

__device__ __forceinline__ unsigned short bfc(float f) {
    return __builtin_bit_cast(unsigned short, (__bf16)f);
}

__device__ __forceinline__ bf16x8 cvt8(float4 a, float4 b) {
    bf16x8 r;
    r[0] = (__bf16)a.x; r[1] = (__bf16)a.y; r[2] = (__bf16)a.z; r[3] = (__bf16)a.w;
    r[4] = (__bf16)b.x; r[5] = (__bf16)b.y; r[6] = (__bf16)b.z; r[7] = (__bf16)b.w;
    return r;
}

// async 16B global -> LDS (linear dest: base + lane*16)
__device__ __forceinline__ void gload16(void* lds, const void* g) {
    __builtin_amdgcn_global_load_lds(
        (const __attribute__((address_space(1))) unsigned int*)g,
        (__attribute__((address_space(3))) unsigned int*)lds, 16, 0, 0);
}

// Prep: mu_out (f32), s_b = x.x + tr(Sigma_b), softplus table,
//       Wt2 fragment-linear: Wt2[((u>>4)*8+kk)*512 + lane*8 + e] = bf16(W[k][u]),
//       lane = lq*16 + (u&15), k = kk*32 + lq*8 + e.
__global__ __launch_bounds__(256) void prep_kernel(
    const float* __restrict__ mu_in, const float* __restrict__ Sigma,
    const float* __restrict__ W, const float* __restrict__ w_sigma,
    float* __restrict__ mu_out, unsigned short* __restrict__ Wt2,
    float* __restrict__ sb, float* __restrict__ sp)
{
    const int b = blockIdx.x;
    const int t = threadIdx.x;

    __shared__ float mrow[DIM];
    mrow[t] = mu_in[b * DIM + t];
    __syncthreads();

    float acc = 0.f;
#pragma unroll 8
    for (int d = 0; d < DIM; ++d) acc += mrow[d] * W[d * UNITS + t];
    mu_out[b * UNITS + t] = acc;

    float xv  = mrow[t];
    float val = xv * xv + Sigma[(size_t)b * DIM * DIM + (size_t)t * (DIM + 1)];
#pragma unroll
    for (int o = 32; o > 0; o >>= 1) val += __shfl_down(val, o);
    __shared__ float wsum[4];
    if ((t & 63) == 0) wsum[t >> 6] = val;
    __syncthreads();
    if (t == 0) sb[b] = wsum[0] + wsum[1] + wsum[2] + wsum[3];

    if (b < UNITS) {
        const int u   = b;
        const int idx = ((u >> 4) * 8 + (t >> 5)) * 512 + ((t >> 3) & 3) * 128
                      + (u & 15) * 8 + (t & 7);
        Wt2[idx] = bfc(W[t * UNITS + u]);
    }
    if (b == 0) sp[t] = log1pf(expf(w_sigma[t]));
}

// Main: one block per (batch b, 128-col v-half). 512 threads = 8 waves.
// R5 structure (per-iter __syncthreads) + register double-buffer of the
// stage-1 Wt2 B-fragments: iter kk+1's frags are loaded BEFORE iter kk's
// barrier, so the barrier's vmcnt(0) drain doubles as their arrival wait.
__global__ __launch_bounds__(512, 4) void sigma_kernel(
    const float* __restrict__ Sigma, const unsigned short* __restrict__ Wt2,
    const float* __restrict__ sb, const float* __restrict__ sp,
    float* __restrict__ out)
{
    // union: [0,65536) = two 32 KB f32 Sigma k-tiles; afterwards Pt[128][264] bf16
    __shared__ __align__(1024) char smem[128 * 264 * 2];
    auto Pt = reinterpret_cast<unsigned short (*)[264]>(smem);

    const int bid     = blockIdx.x;
    const int logical = (bid & 7) * 128 + (bid >> 3);   // XCD-chunked, bijective
    const int b       = logical >> 1;
    const int h       = logical & 1;
    const int v0      = h * 128;
    const int s8      = h * 8;

    const int tid  = threadIdx.x;
    const int lane = tid & 63;
    const int w    = tid >> 6;     // 0..7
    const int lq   = lane >> 4;    // 0..3
    const int lr   = lane & 15;    // 0..15
    const int m0   = w * 32;

    const float* S = Sigma + (size_t)b * DIM * DIM;
    float*       O = out   + (size_t)b * UNITS * UNITS;
    const float  sbv = sb[b];

    // staging: wave w stages rows [w*32, w*32+32); lane l -> row +8q + (l>>3),
    // source chunk (l&7)^(l>>3) (XOR involution), LDS dest linear.
    const int rsub = lane >> 3;
    const int csrc = (lane & 7) ^ rsub;
    const char* gbase = (const char*)S + (size_t)(w * 32 + rsub) * 1024 + csrc * 16;
    const int   ldsw  = w * 4096;

    // stage-1 A-frag read offsets (same XOR on read)
    const int h7 = lr & 7;
    const int a0r = (m0 + lr) * 128;
    const int a1r = (m0 + 16 + lr) * 128;
    const int c0  = ((2 * lq + 0) ^ h7) * 16;
    const int c1  = ((2 * lq + 1) ^ h7) * 16;

    const unsigned short* wtbase = Wt2 + (size_t)s8 * 8 * 512 + lane * 8;

    f32x4 acc[2][8];
#pragma unroll
    for (int i = 0; i < 2; ++i)
#pragma unroll
        for (int j = 0; j < 8; ++j)
#pragma unroll
            for (int r = 0; r < 4; ++r) acc[i][j][r] = 0.f;

    // ---- prologue: stage tile 0; prefetch kk=0's B-frags; one drain ----
#pragma unroll
    for (int q = 0; q < 4; ++q)
        gload16(smem + ldsw + q * 1024, gbase + q * 8192);

    bf16x8 bcur[8];
#pragma unroll
    for (int j = 0; j < 8; ++j)
        bcur[j] = ld_bf8(wtbase + (size_t)(j * 8 + 0) * 512);

    __syncthreads();

    // ---- Stage 1: P[d][v] = sum_e Sigma[d][e] * W[e][v] ----
#pragma unroll
    for (int kk = 0; kk < 8; ++kk) {
        const int cur = (kk & 1) * 32768;

        // prefetch tile kk+1 into the other LDS buffer (drained by barrier)
        if (kk < 7) {
            const int nxt = cur ^ 32768;
#pragma unroll
            for (int q = 0; q < 4; ++q)
                gload16(smem + nxt + ldsw + q * 1024,
                        gbase + q * 8192 + (kk + 1) * 128);
        }

        // prefetch kk+1's B-frags into registers (drained by barrier)
        bf16x8 bnxt[8];
        if (kk < 7) {
#pragma unroll
            for (int j = 0; j < 8; ++j)
                bnxt[j] = ld_bf8(wtbase + (size_t)(j * 8 + kk + 1) * 512);
        }

        // per-wave-private frag reads from LDS (tile kk, ready)
        float4 fa0 = *reinterpret_cast<const float4*>(smem + cur + a0r + c0);
        float4 fb0 = *reinterpret_cast<const float4*>(smem + cur + a0r + c1);
        float4 fa1 = *reinterpret_cast<const float4*>(smem + cur + a1r + c0);
        float4 fb1 = *reinterpret_cast<const float4*>(smem + cur + a1r + c1);
        bf16x8 af0 = cvt8(fa0, fb0);
        bf16x8 af1 = cvt8(fa1, fb1);

#pragma unroll
        for (int j = 0; j < 8; ++j) {
            acc[0][j] = __builtin_amdgcn_mfma_f32_16x16x32_bf16(af0, bcur[j], acc[0][j], 0, 0, 0);
            acc[1][j] = __builtin_amdgcn_mfma_f32_16x16x32_bf16(af1, bcur[j], acc[1][j], 0, 0, 0);
        }

        if (kk < 7) {
#pragma unroll
            for (int j = 0; j < 8; ++j) bcur[j] = bnxt[j];
        }

        // barrier: protects next tile's LDS buffer AND waits both prefetches
        __syncthreads();
    }

    // ---- write P^T into LDS ----
#pragma unroll
    for (int i = 0; i < 2; ++i) {
#pragma unroll
        for (int j = 0; j < 8; ++j) {
            const int d0 = m0 + 16 * i + 4 * lq;
            const int vl = 16 * j + lr;
            uint2 pk;
            pk.x = (unsigned)bfc(acc[i][j][0]) | ((unsigned)bfc(acc[i][j][1]) << 16);
            pk.y = (unsigned)bfc(acc[i][j][2]) | ((unsigned)bfc(acc[i][j][3]) << 16);
            *reinterpret_cast<uint2*>(&Pt[vl][d0]) = pk;
        }
    }
    __syncthreads();

    // ---- Stage 2: out[u][v] = sum_d W[d][u] * P[d][v] (barrier-free) ----
#pragma unroll
    for (int i = 0; i < 2; ++i)
#pragma unroll
        for (int j = 0; j < 8; ++j)
#pragma unroll
            for (int r = 0; r < 4; ++r) acc[i][j][r] = 0.f;

#pragma unroll
    for (int kk = 0; kk < 8; ++kk) {
        bf16x8 af0 = ld_bf8(Wt2 + (size_t)((w * 2 + 0) * 8 + kk) * 512 + lane * 8);
        bf16x8 af1 = ld_bf8(Wt2 + (size_t)((w * 2 + 1) * 8 + kk) * 512 + lane * 8);
#pragma unroll
        for (int j = 0; j < 8; ++j) {
            bf16x8 pb = *reinterpret_cast<const bf16x8*>(&Pt[16 * j + lr][kk * 32 + 8 * lq]);
            acc[0][j] = __builtin_amdgcn_mfma_f32_16x16x32_bf16(af0, pb, acc[0][j], 0, 0, 0);
            acc[1][j] = __builtin_amdgcn_mfma_f32_16x16x32_bf16(af1, pb, acc[1][j], 0, 0, 0);
        }
    }

    // ---- Epilogue: diag add, finite cleanup, abs-diag, store ----
#pragma unroll
    for (int i = 0; i < 2; ++i) {
#pragma unroll
        for (int j = 0; j < 8; ++j) {
            const int   vg  = v0 + 16 * j + lr;
            const float spv = sp[vg];
#pragma unroll
            for (int r = 0; r < 4; ++r) {
                const int u = m0 + 16 * i + 4 * lq + r;
                float val = acc[i][j][r];
                if (u == vg) val += sbv * spv;
                val = __builtin_isfinite(val) ? val : 0.0f;
                if (u == vg) val = fabsf(val);
                O[(size_t)u * UNITS + vg] = val;
            }
        }
    }
}

extern "C" void kernel_launch(void* const* d_in, const int* in_sizes, int n_in,
                              void* d_out, int out_size, void* d_ws, size_t ws_size,
                              hipStream_t stream) {
    const float* mu_in  = (const float*)d_in[0];
    const float* Sigma  = (const float*)d_in[1];
    const float* w_mu   = (const float*)d_in[2];
    const float* w_sig  = (const float*)d_in[3];

    float* mu_out  = (float*)d_out;
    float* Sig_out = (float*)d_out + BATCH * UNITS;

    unsigned short* Wt2 = (unsigned short*)d_ws;                      // 131072 B
    float* sb = (float*)((char*)d_ws + (size_t)DIM * UNITS * 2);      // 512 f32
    float* sp = sb + BATCH;                                           // 256 f32

    prep_kernel<<<BATCH, 256, 0, stream>>>(mu_in, Sigma, w_mu, w_sig, mu_out, Wt2, sb, sp);
    sigma_kernel<<<BATCH * 2, 512, 0, stream>>>(Sigma, Wt2, sb, sp, Sig_out);
}

// Round 9
// 78.283 us; speedup vs baseline: 1.7817x; 1.7817x over previous
//
#include <hip/hip_runtime.h>

#define BATCH 512
#define DIM   256
#define UNITS 256

typedef __bf16 bf16x8 __attribute__((ext_vector_type(8)));
typedef float  f32x4  __attribute__((ext_vector_type(4)));

__device__ __forceinline__ bf16x8 ld_bf8(const unsigned short* p) {
    uint4 u = *reinterpret_cast<const uint4*>(p);
    return __builtin_bit_cast(bf16x8, u);
}

__device__ __forceinline__ unsigned short bfc(float f) {
    return __builtin_bit_cast(unsigned short, (__bf16)f);
}

__device__ __forceinline__ bf16x8 cvt8(float4 a, float4 b) {
    bf16x8 r;
    r[0] = (__bf16)a.x; r[1] = (__bf16)a.y; r[2] = (__bf16)a.z; r[3] = (__bf16)a.w;
    r[4] = (__bf16)b.x; r[5] = (__bf16)b.y; r[6] = (__bf16)b.z; r[7] = (__bf16)b.w;
    return r;
}

// async 16B global -> LDS (linear dest: wave-uniform base + lane*16)
__device__ __forceinline__ void gload16(void* lds, const void* g) {
    __builtin_amdgcn_global_load_lds(
        (const __attribute__((address_space(1))) unsigned int*)g,
        (__attribute__((address_space(3))) unsigned int*)lds, 16, 0, 0);
}

// Prep: mu_out (f32), s_b = x.x + tr(Sigma_b), softplus table,
//       Wt2 fragment-linear: Wt2[((u>>4)*8+kk)*512 + lane*8 + e] = bf16(W[k][u]),
//       lane = lq*16 + (u&15), k = kk*32 + lq*8 + e.
__global__ __launch_bounds__(256) void prep_kernel(
    const float* __restrict__ mu_in, const float* __restrict__ Sigma,
    const float* __restrict__ W, const float* __restrict__ w_sigma,
    float* __restrict__ mu_out, unsigned short* __restrict__ Wt2,
    float* __restrict__ sb, float* __restrict__ sp)
{
    const int b = blockIdx.x;
    const int t = threadIdx.x;

    __shared__ float mrow[DIM];
    mrow[t] = mu_in[b * DIM + t];
    __syncthreads();

    float acc = 0.f;
#pragma unroll 8
    for (int d = 0; d < DIM; ++d) acc += mrow[d] * W[d * UNITS + t];
    mu_out[b * UNITS + t] = acc;

    float xv  = mrow[t];
    float val = xv * xv + Sigma[(size_t)b * DIM * DIM + (size_t)t * (DIM + 1)];
#pragma unroll
    for (int o = 32; o > 0; o >>= 1) val += __shfl_down(val, o);
    __shared__ float wsum[4];
    if ((t & 63) == 0) wsum[t >> 6] = val;
    __syncthreads();
    if (t == 0) sb[b] = wsum[0] + wsum[1] + wsum[2] + wsum[3];

    if (b < UNITS) {
        const int u   = b;
        const int idx = ((u >> 4) * 8 + (t >> 5)) * 512 + ((t >> 3) & 3) * 128
                      + (u & 15) * 8 + (t & 7);
        Wt2[idx] = bfc(W[t * UNITS + u]);
    }
    if (b == 0) sp[t] = log1pf(expf(w_sigma[t]));
}

// Main: one block per (batch b, 128-col v-half). 512 threads = 8 waves.
// R5 structure (per-iter __syncthreads, gload_lds Sigma dbuf) + NEW:
// stage-1 Wt2 B-frag slab staged to LDS ONCE per block (wave w stages
// frag j=w; previously all 8 waves loaded the identical 8 KB -> 8x
// redundant VMEM, 512 KB/block of the ~900 KB total).
__global__ __launch_bounds__(512, 4) void sigma_kernel(
    const float* __restrict__ Sigma, const unsigned short* __restrict__ Wt2,
    const float* __restrict__ sb, const float* __restrict__ sp,
    float* __restrict__ out)
{
    // [0,65536): two 32 KB f32 Sigma k-tiles (double buffer)
    // [65536,81920): two 8 KB Wt2 B-frag slabs (double buffer)
    // Pt[128][264] bf16 (67584 B) unions over [0,67584) after stage 1
    __shared__ __align__(1024) char smem[81920];
    auto Pt = reinterpret_cast<unsigned short (*)[264]>(smem);
    char* bsh = smem + 65536;

    const int bid     = blockIdx.x;
    const int logical = (bid & 7) * 128 + (bid >> 3);   // XCD-chunked, bijective
    const int b       = logical >> 1;
    const int h       = logical & 1;
    const int v0      = h * 128;
    const int s8      = h * 8;

    const int tid  = threadIdx.x;
    const int lane = tid & 63;
    const int w    = tid >> 6;     // 0..7
    const int lq   = lane >> 4;    // 0..3
    const int lr   = lane & 15;    // 0..15
    const int m0   = w * 32;

    const float* S = Sigma + (size_t)b * DIM * DIM;
    float*       O = out   + (size_t)b * UNITS * UNITS;
    const float  sbv = sb[b];

    // Sigma staging: wave w stages rows [w*32, w*32+32); lane l -> row +8q+(l>>3),
    // source chunk (l&7)^(l>>3) (XOR involution), LDS dest linear.
    const int rsub = lane >> 3;
    const int csrc = (lane & 7) ^ rsub;
    const char* gbase = (const char*)S + (size_t)(w * 32 + rsub) * 1024 + csrc * 16;
    const int   ldsw  = w * 4096;

    // Wt2 slab staging: wave w stages fragment j=w (1 KB) per k-iter.
    const unsigned short* wslab = Wt2 + (size_t)(s8 + w) * 8 * 512;   // + kk*512

    // stage-1 A-frag read offsets (same XOR on read)
    const int h7 = lr & 7;
    const int a0r = (m0 + lr) * 128;
    const int a1r = (m0 + 16 + lr) * 128;
    const int c0  = ((2 * lq + 0) ^ h7) * 16;
    const int c1  = ((2 * lq + 1) ^ h7) * 16;

    f32x4 acc[2][8];
#pragma unroll
    for (int i = 0; i < 2; ++i)
#pragma unroll
        for (int j = 0; j < 8; ++j)
#pragma unroll
            for (int r = 0; r < 4; ++r) acc[i][j][r] = 0.f;

    // ---- prologue: stage Sigma tile 0 + B-slab 0 ----
#pragma unroll
    for (int q = 0; q < 4; ++q)
        gload16(smem + ldsw + q * 1024, gbase + q * 8192);
    gload16(bsh + w * 1024, wslab);
    __syncthreads();

    // ---- Stage 1: P[d][v] = sum_e Sigma[d][e] * W[e][v] ----
#pragma unroll
    for (int kk = 0; kk < 8; ++kk) {
        const int cur  = (kk & 1) * 32768;
        char*     bcur = bsh + (kk & 1) * 8192;

        // prefetch tile kk+1 (Sigma: 4 gloads; Wt2 slab: 1 gload per wave)
        if (kk < 7) {
            const int nxt = cur ^ 32768;
#pragma unroll
            for (int q = 0; q < 4; ++q)
                gload16(smem + nxt + ldsw + q * 1024,
                        gbase + q * 8192 + (kk + 1) * 128);
            gload16(bsh + ((kk + 1) & 1) * 8192 + w * 1024, wslab + (kk + 1) * 512);
        }

        // A-frags: per-wave-private Sigma rows (XOR-swizzled)
        float4 fa0 = *reinterpret_cast<const float4*>(smem + cur + a0r + c0);
        float4 fb0 = *reinterpret_cast<const float4*>(smem + cur + a0r + c1);
        float4 fa1 = *reinterpret_cast<const float4*>(smem + cur + a1r + c0);
        float4 fb1 = *reinterpret_cast<const float4*>(smem + cur + a1r + c1);
        bf16x8 af0 = cvt8(fa0, fb0);
        bf16x8 af1 = cvt8(fa1, fb1);

        // B-frags: shared slab from LDS (contiguous lane*16 -> ds_read_b128)
#pragma unroll
        for (int j = 0; j < 8; ++j) {
            bf16x8 bf = *reinterpret_cast<const bf16x8*>(bcur + j * 1024 + lane * 16);
            acc[0][j] = __builtin_amdgcn_mfma_f32_16x16x32_bf16(af0, bf, acc[0][j], 0, 0, 0);
            acc[1][j] = __builtin_amdgcn_mfma_f32_16x16x32_bf16(af1, bf, acc[1][j], 0, 0, 0);
        }

        // barrier: protects next tile's LDS buffers AND drains prefetches
        __syncthreads();
    }

    // ---- write P^T into LDS ----
#pragma unroll
    for (int i = 0; i < 2; ++i) {
#pragma unroll
        for (int j = 0; j < 8; ++j) {
            const int d0 = m0 + 16 * i + 4 * lq;
            const int vl = 16 * j + lr;
            uint2 pk;
            pk.x = (unsigned)bfc(acc[i][j][0]) | ((unsigned)bfc(acc[i][j][1]) << 16);
            pk.y = (unsigned)bfc(acc[i][j][2]) | ((unsigned)bfc(acc[i][j][3]) << 16);
            *reinterpret_cast<uint2*>(&Pt[vl][d0]) = pk;
        }
    }
    __syncthreads();

    // ---- Stage 2: out[u][v] = sum_d W[d][u] * P[d][v] (barrier-free) ----
#pragma unroll
    for (int i = 0; i < 2; ++i)
#pragma unroll
        for (int j = 0; j < 8; ++j)
#pragma unroll
            for (int r = 0; r < 4; ++r) acc[i][j][r] = 0.f;

#pragma unroll
    for (int kk = 0; kk < 8; ++kk) {
        bf16x8 af0 = ld_bf8(Wt2 + (size_t)((w * 2 + 0) * 8 + kk) * 512 + lane * 8);
        bf16x8 af1 = ld_bf8(Wt2 + (size_t)((w * 2 + 1) * 8 + kk) * 512 + lane * 8);
#pragma unroll
        for (int j = 0; j < 8; ++j) {
            bf16x8 pb = *reinterpret_cast<const bf16x8*>(&Pt[16 * j + lr][kk * 32 + 8 * lq]);
            acc[0][j] = __builtin_amdgcn_mfma_f32_16x16x32_bf16(af0, pb, acc[0][j], 0, 0, 0);
            acc[1][j] = __builtin_amdgcn_mfma_f32_16x16x32_bf16(af1, pb, acc[1][j], 0, 0, 0);
        }
    }

    // ---- Epilogue: diag add, finite cleanup, abs-diag, store ----
#pragma unroll
    for (int i = 0; i < 2; ++i) {
#pragma unroll
        for (int j = 0; j < 8; ++j) {
            const int   vg  = v0 + 16 * j + lr;
            const float spv = sp[vg];
#pragma unroll
            for (int r = 0; r < 4; ++r) {
                const int u = m0 + 16 * i + 4 * lq + r;
                float val = acc[i][j][r];
                if (u == vg) val += sbv * spv;
                val = __builtin_isfinite(val) ? val : 0.0f;
                if (u == vg) val = fabsf(val);
                O[(size_t)u * UNITS + vg] = val;
            }
        }
    }
}

extern "C" void kernel_launch(void* const* d_in, const int* in_sizes, int n_in,
                              void* d_out, int out_size, void* d_ws, size_t ws_size,
                              hipStream_t stream) {
    const float* mu_in  = (const float*)d_in[0];
    const float* Sigma  = (const float*)d_in[1];
    const float* w_mu   = (const float*)d_in[2];
    const float* w_sig  = (const float*)d_in[3];

    float* mu_out  = (float*)d_out;
    float* Sig_out = (float*)d_out + BATCH * UNITS;

    unsigned short* Wt2 = (unsigned short*)d_ws;                      // 131072 B
    float* sb = (float*)((char*)d_ws + (size_t)DIM * UNITS * 2);      // 512 f32
    float* sp = sb + BATCH;                                           // 256 f32

    prep_kernel<<<BATCH, 256, 0, stream>>>(mu_in, Sigma, w_mu, w_sig, mu_out, Wt2, sb, sp);
    sigma_kernel<<<BATCH * 2, 512, 0, stream>>>(Sigma, Wt2, sb, sp, Sig_out);
}